// Round 1
// baseline (293.362 us; speedup 1.0000x reference)
//
#include <hip/hip_runtime.h>

#define N_NODES 50000
#define N_EDGES 800000
#define D 128
#define HP 128              // histogram / fill partition blocks
#define EPB (N_EDGES / HP)  // 6250 edges per partition
#define NW (N_NODES / 2)    // 25000 packed u32 words (2 nodes/word)
#define NWB 98              // ceil(NW/256) reduce/scan blocks (512 nodes each)
#define NBLK 782            // ceil(N_NODES/64) fused gather+gemm blocks

typedef __attribute__((ext_vector_type(8))) short short8;   // 8 bf16
typedef __attribute__((ext_vector_type(4))) float f32x4;

__device__ __forceinline__ unsigned short f2bf(float f) {
    unsigned u = __float_as_uint(f);
    return (unsigned short)((u + 0x7FFFu + ((u >> 16) & 1u)) >> 16);  // RNE
}
__device__ __forceinline__ float bf2f(unsigned short h) {
    return __uint_as_float((unsigned)h << 16);
}

// accumulate 16 bf16 (packed in two uint4) into 16 f32
__device__ __forceinline__ void acc16(float* a, uint4 v0, uint4 v1) {
    unsigned w0 = v0.x, w1 = v0.y, w2 = v0.z, w3 = v0.w;
    unsigned w4 = v1.x, w5 = v1.y, w6 = v1.z, w7 = v1.w;
    a[0]  += __uint_as_float(w0 << 16);  a[1]  += __uint_as_float(w0 & 0xFFFF0000u);
    a[2]  += __uint_as_float(w1 << 16);  a[3]  += __uint_as_float(w1 & 0xFFFF0000u);
    a[4]  += __uint_as_float(w2 << 16);  a[5]  += __uint_as_float(w2 & 0xFFFF0000u);
    a[6]  += __uint_as_float(w3 << 16);  a[7]  += __uint_as_float(w3 & 0xFFFF0000u);
    a[8]  += __uint_as_float(w4 << 16);  a[9]  += __uint_as_float(w4 & 0xFFFF0000u);
    a[10] += __uint_as_float(w5 << 16);  a[11] += __uint_as_float(w5 & 0xFFFF0000u);
    a[12] += __uint_as_float(w6 << 16);  a[13] += __uint_as_float(w6 & 0xFFFF0000u);
    a[14] += __uint_as_float(w7 << 16);  a[15] += __uint_as_float(w7 & 0xFFFF0000u);
}

// ---- degrees via per-block LDS histograms (no global atomics) ----
// LDS word w packs: in[2w](b0) | out[2w](b1) | in[2w+1](b2) | out[2w+1](b3), u8 each.
// Block 0 additionally zeroes the degree-sort bins (consumed by k_reduce, next kernel).
__global__ __launch_bounds__(256) void k_hist(const int2* __restrict__ el2,
                                              unsigned int* __restrict__ partials,
                                              int* __restrict__ bins) {
    __shared__ unsigned int h[NW];  // 100 KB
    int t = threadIdx.x;
    if (blockIdx.x == 0)
        for (int i = t; i < 2048; i += 256) bins[i] = 0;
    for (int i = t; i < NW / 4; i += 256) ((uint4*)h)[i] = make_uint4(0, 0, 0, 0);
    __syncthreads();
    const int2* p = el2 + blockIdx.x * EPB;
    for (int i = t; i < EPB; i += 256) {
        int2 st = p[i];
        atomicAdd(&h[st.x >> 1], 1u << ((st.x & 1) * 16));       // in-degree byte
        atomicAdd(&h[st.y >> 1], 256u << ((st.y & 1) * 16));     // out-degree byte
    }
    __syncthreads();
    uint4* dst = (uint4*)(partials + (size_t)blockIdx.x * NW);
    for (int i = t; i < NW / 4; i += 256) dst[i] = ((uint4*)h)[i];
}

// ---- fused: degree totals + cross-block exclusive prefixes (brel) + 512-node
// block sums + sharded degree histogram (for the scheduling sort). ----
// NOTE: so = sum of (v>>8)&0x00FF00FF; out[2w] in so[15:0], out[2w+1] in so[31:16].
__global__ __launch_bounds__(256) void k_reduce(const unsigned int* __restrict__ partials,
                                                unsigned char* __restrict__ brel,
                                                int* __restrict__ deg_in,
                                                int* __restrict__ deg_out,
                                                int* __restrict__ blk_sum,
                                                int* __restrict__ bins) {
    __shared__ int sc[256];
    __shared__ int hb[256];
    int t = threadIdx.x;
    hb[t] = 0;
    int w = blockIdx.x * 256 + t;
    unsigned int si = 0, so = 0;
    if (w < NW) {
        for (int p = 0; p < HP; ++p) {
            unsigned pre = (so & 0xFFu) | (((so >> 16) & 0xFFu) << 8);
            ((unsigned short*)(brel + (size_t)p * N_NODES))[w] = (unsigned short)pre;
            unsigned int v = partials[p * NW + w];
            si += v & 0x00FF00FFu;
            so += (v >> 8) & 0x00FF00FFu;
        }
        *(int2*)&deg_in[2 * w]  = make_int2(si & 0xFFFF, si >> 16);
        *(int2*)&deg_out[2 * w] = make_int2(so & 0xFFFF, so >> 16);
    }
    __syncthreads();  // hb zeroed and visible
    if (w < NW) {
        int d0 = (int)(so & 0xFFFFu), d1 = (int)(so >> 16);
        atomicAdd(&hb[d0 < 255 ? d0 : 255], 1);
        atomicAdd(&hb[d1 < 255 ? d1 : 255], 1);
    }
    sc[t] = (w < NW) ? (int)((so & 0xFFFFu) + (so >> 16)) : 0;
    __syncthreads();  // also orders the hb atomics above
    for (int s = 128; s > 0; s >>= 1) {
        if (t < s) sc[t] += sc[t + s];
        __syncthreads();
    }
    if (t == 0) blk_sum[blockIdx.x] = sc[0];
    // shard = blockIdx&7 (same mapping reused by k_scan_c's placement)
    if (hb[t]) atomicAdd(&bins[t * 8 + (blockIdx.x & 7)], hb[t]);
}

// exclusive scan of the NWB block sums + exclusive scan of the 2048 (deg,shard)
// bins into the sort cursors (single block)
__global__ void k_scan_b(const int* __restrict__ blk_sum, int* __restrict__ blk_off,
                         const int* __restrict__ bins, int* __restrict__ cursor) {
    __shared__ int sc[256];
    int t = threadIdx.x;
    int v = (t < NWB) ? blk_sum[t] : 0;
    sc[t] = v;
    __syncthreads();
    for (int off = 1; off < 256; off <<= 1) {
        int a = (t >= off) ? sc[t - off] : 0;
        __syncthreads();
        sc[t] += a;
        __syncthreads();
    }
    if (t < NWB) blk_off[t] = sc[t] - v;  // exclusive
    __syncthreads();
    // degree bins: 8 consecutive (deg-major, shard-minor) per thread
    int loc[8], s = 0;
    #pragma unroll
    for (int i = 0; i < 8; ++i) { loc[i] = bins[t * 8 + i]; s += loc[i]; }
    sc[t] = s;
    __syncthreads();
    for (int off = 1; off < 256; off <<= 1) {
        int a = (t >= off) ? sc[t - off] : 0;
        __syncthreads();
        sc[t] += a;
        __syncthreads();
    }
    int base = sc[t] - s;  // exclusive
    #pragma unroll
    for (int i = 0; i < 8; ++i) { cursor[t * 8 + i] = base; base += loc[i]; }
}

// row_start over 512 nodes/block (2 per thread) + degree-sort placement.
// order[] is DESCENDING degree so heavy blocks launch first (better makespan).
// Any permutation is functionally correct — order only affects scheduling.
__global__ void k_scan_c(const int* __restrict__ deg_out, const int* __restrict__ blk_off,
                         int* __restrict__ row_start, int* __restrict__ cursor,
                         int* __restrict__ order) {
    __shared__ int sc[256];
    int t = threadIdx.x;
    int w = blockIdx.x * 256 + t;
    int v0 = 0, v1 = 0;
    if (w < NW) { int2 d2 = *(const int2*)&deg_out[2 * w]; v0 = d2.x; v1 = d2.y; }
    int pair = v0 + v1;
    sc[t] = pair;
    __syncthreads();
    for (int off = 1; off < 256; off <<= 1) {
        int a = (t >= off) ? sc[t - off] : 0;
        __syncthreads();
        sc[t] += a;
        __syncthreads();
    }
    if (w < NW) {
        int base = blk_off[blockIdx.x] + sc[t] - pair;
        *(int2*)&row_start[2 * w] = make_int2(base, base + v0);
        int sh = blockIdx.x & 7;
        int p0 = atomicAdd(&cursor[(v0 < 255 ? v0 : 255) * 8 + sh], 1);
        int p1 = atomicAdd(&cursor[(v1 < 255 ? v1 : 255) * 8 + sh], 1);
        order[N_NODES - 1 - p0] = 2 * w;
        order[N_NODES - 1 - p1] = 2 * w + 1;
    }
}

// ---- counting-sort placement, NO global atomics; srcs stored as u16 ----
__global__ __launch_bounds__(256) void k_fill(const int2* __restrict__ el2,
                                              const int* __restrict__ row_start,
                                              const unsigned char* __restrict__ brel,
                                              unsigned short* __restrict__ srcs) {
    __shared__ unsigned int cur[NW];  // 100 KB packed u16 cursors
    int t = threadIdx.x;
    for (int i = t; i < NW / 4; i += 256) ((uint4*)cur)[i] = make_uint4(0, 0, 0, 0);
    __syncthreads();
    const int2* p = el2 + blockIdx.x * EPB;
    const unsigned char* br = brel + (size_t)blockIdx.x * N_NODES;
    for (int i = t; i < EPB; i += 256) {
        int2 st = p[i];
        int n = st.y;
        unsigned old = atomicAdd(&cur[n >> 1], 1u << ((n & 1) * 16));
        int rank = (old >> ((n & 1) * 16)) & 0xFFFF;
        srcs[row_start[n] + (int)br[n] + rank] = (unsigned short)st.x;
    }
}

// ---- xst[n][128] = bf16(rsqrt(deg_in[n]+1) * x[n][:]) — row-contiguous 256B rows ----
__global__ void k_prescale(const float4* __restrict__ x4, const int* __restrict__ deg_in,
                           uint4* __restrict__ xst) {
    int g = blockIdx.x * blockDim.x + threadIdx.x;  // N*16 groups of 8 elems
    int n = g >> 4, part = g & 15;
    float rs = rsqrtf((float)(deg_in[n] + 1));
    float4 a = x4[g * 2], c = x4[g * 2 + 1];
    uint4 o;
    o.x = f2bf(rs * a.x) | ((unsigned)f2bf(rs * a.y) << 16);
    o.y = f2bf(rs * a.z) | ((unsigned)f2bf(rs * a.w) << 16);
    o.z = f2bf(rs * c.x) | ((unsigned)f2bf(rs * c.y) << 16);
    o.w = f2bf(rs * c.z) | ((unsigned)f2bf(rs * c.w) << 16);
    xst[(size_t)n * 16 + part] = o;  // uint4 units (8 bf16)
}

// ---- fused gather + GEMM: per block 64 degree-sorted nodes.
// Phase 1: 8 lanes/node, each lane accumulates a 16-feature slice in f32 regs
//          (full 256B source row per edge, coalesced across the 8 lanes).
// Phase 2: scale by rd, cvt bf16 -> LDS A-tile, 8 waves do 64x128 MFMA GEMM,
//          bias+relu, scatter rows to out via order[].
__global__ __launch_bounds__(512, 4) void k_gg(const float* __restrict__ W,
                                               const float* __restrict__ bias,
                                               const unsigned short* __restrict__ xst,
                                               const unsigned short* __restrict__ srcs,
                                               const int* __restrict__ row_start,
                                               const int* __restrict__ deg_out,
                                               const int* __restrict__ order,
                                               float* __restrict__ out) {
    __shared__ unsigned short Wl[128 * 136];  // 34.8 KB
    __shared__ unsigned short As[64 * 136];   // 17.4 KB
    const int tid = threadIdx.x;

    // stage W -> bf16 (once per block)
    for (int i = tid; i < 128 * 32; i += 512) {
        int r = i >> 5, c = i & 31;
        float4 w4 = *(const float4*)&W[r * D + c * 4];
        ushort4 hh;
        hh.x = f2bf(w4.x); hh.y = f2bf(w4.y); hh.z = f2bf(w4.z); hh.w = f2bf(w4.w);
        *(ushort4*)&Wl[r * 136 + c * 4] = hh;
    }

    // ---- phase 1: gather ----
    const int slot = tid >> 3;            // As row 0..63
    const int d = tid & 7;                // 16-feature slice
    const int gslot = blockIdx.x * 64 + slot;
    float acc[16];
    #pragma unroll
    for (int i = 0; i < 16; ++i) acc[i] = 0.f;

    if (gslot < N_NODES) {
        const int node = order[gslot];
        const int cnt = deg_out[node];
        const uint4* xb = (const uint4*)xst;
        const int dof = d * 2;
        {   // self term (already rs-scaled)
            const uint4* xr = xb + (size_t)node * 16 + dof;
            acc16(acc, xr[0], xr[1]);
        }
        const unsigned short* p = srcs + row_start[node];
        int k = 0;
        for (; k + 4 <= cnt; k += 4) {
            int s0 = p[k], s1 = p[k + 1], s2 = p[k + 2], s3 = p[k + 3];
            const uint4* r0 = xb + (size_t)s0 * 16 + dof;
            const uint4* r1 = xb + (size_t)s1 * 16 + dof;
            const uint4* r2 = xb + (size_t)s2 * 16 + dof;
            const uint4* r3 = xb + (size_t)s3 * 16 + dof;
            uint4 a0 = r0[0], b0 = r0[1];
            uint4 a1 = r1[0], b1 = r1[1];
            uint4 a2 = r2[0], b2 = r2[1];
            uint4 a3 = r3[0], b3 = r3[1];
            acc16(acc, a0, b0); acc16(acc, a1, b1);
            acc16(acc, a2, b2); acc16(acc, a3, b3);
        }
        for (; k < cnt; ++k) {
            const uint4* r0 = xb + (size_t)p[k] * 16 + dof;
            acc16(acc, r0[0], r0[1]);
        }
        float rd = rsqrtf((float)(cnt + 1));
        #pragma unroll
        for (int i = 0; i < 16; ++i) acc[i] *= rd;
    }
    {   // pack 16 f32 -> 16 bf16 -> LDS (invalid slots write zeros; no early return!)
        unsigned wpk[8];
        #pragma unroll
        for (int i = 0; i < 8; ++i)
            wpk[i] = (unsigned)f2bf(acc[2 * i]) | ((unsigned)f2bf(acc[2 * i + 1]) << 16);
        uint4* dst = (uint4*)&As[slot * 136 + d * 16];
        dst[0] = make_uint4(wpk[0], wpk[1], wpk[2], wpk[3]);
        dst[1] = make_uint4(wpk[4], wpk[5], wpk[6], wpk[7]);
    }
    __syncthreads();

    // ---- phase 2: 64x128 GEMM, 8 waves = 4 row-tiles x 2 col-halves ----
    const int wv = tid >> 6, lane = tid & 63, ml = lane & 15, q = lane >> 4;
    const int rt = wv & 3, half = wv >> 2;
    const int arow = rt * 16 + ml;
    short8 a[4];
    #pragma unroll
    for (int kt = 0; kt < 4; ++kt)
        a[kt] = *(const short8*)&As[arow * 136 + kt * 32 + q * 8];

    f32x4 accm[4];
    #pragma unroll
    for (int jj = 0; jj < 4; ++jj) accm[jj] = (f32x4){0.f, 0.f, 0.f, 0.f};
    #pragma unroll
    for (int jj = 0; jj < 4; ++jj) {
        #pragma unroll
        for (int kt = 0; kt < 4; ++kt) {
            short8 bw = *(const short8*)&Wl[(half * 64 + jj * 16 + ml) * 136 + kt * 32 + q * 8];
            accm[jj] = __builtin_amdgcn_mfma_f32_16x16x32_bf16(a[kt], bw, accm[jj], 0, 0, 0);
        }
    }
    #pragma unroll
    for (int jj = 0; jj < 4; ++jj) {
        float bj = bias[half * 64 + jj * 16 + ml];
        #pragma unroll
        for (int r4 = 0; r4 < 4; ++r4) {
            int s = rt * 16 + q * 4 + r4;
            int gs = blockIdx.x * 64 + s;
            if (gs < N_NODES) {
                int nd = order[gs];
                float v = accm[jj][r4] + bj;
                out[nd * D + half * 64 + jj * 16 + ml] = v > 0.f ? v : 0.f;
            }
        }
    }
}

extern "C" void kernel_launch(void* const* d_in, const int* in_sizes, int n_in,
                              void* d_out, int out_size, void* d_ws, size_t ws_size,
                              hipStream_t stream) {
    const int*   el = (const int*)d_in[0];
    const float* x  = (const float*)d_in[1];
    const float* W  = (const float*)d_in[2];
    const float* b  = (const float*)d_in[3];
    float* out = (float*)d_out;

    // workspace layout (~34.6 MB)
    unsigned int* partials = (unsigned int*)d_ws;                            // HP*NW u32 = 12.8M
    unsigned short* xst    = (unsigned short*)(partials + (size_t)HP * NW);  // N*128 bf16 = 12.8M
    unsigned char* brel    = (unsigned char*)(xst + (size_t)N_NODES * D);    // HP*N u8 = 6.4M
    unsigned short* srcs   = (unsigned short*)(brel + (size_t)HP * N_NODES); // E u16 = 1.6M
    int* deg_in    = (int*)(srcs + N_EDGES);                                 // N
    int* deg_out   = deg_in + N_NODES;                                       // N
    int* row_start = deg_out + N_NODES;                                      // N
    int* blk_sum   = row_start + N_NODES;                                    // 256
    int* blk_off   = blk_sum + 256;                                          // 256
    int* bins      = blk_off + 256;                                          // 2048
    int* cursor    = bins + 2048;                                            // 2048
    int* order     = cursor + 2048;                                          // N

    k_hist<<<HP, 256, 0, stream>>>((const int2*)el, partials, bins);
    k_reduce<<<NWB, 256, 0, stream>>>(partials, brel, deg_in, deg_out, blk_sum, bins);
    k_scan_b<<<1, 256, 0, stream>>>(blk_sum, blk_off, bins, cursor);
    k_scan_c<<<NWB, 256, 0, stream>>>(deg_out, blk_off, row_start, cursor, order);
    k_prescale<<<N_NODES * 16 / 256, 256, 0, stream>>>((const float4*)x, deg_in, (uint4*)xst);
    k_fill<<<HP, 256, 0, stream>>>((const int2*)el, row_start, brel, srcs);
    k_gg<<<NBLK, 512, 0, stream>>>(W, b, xst, srcs, row_start, deg_out, order, out);
}

// Round 2
// 192.696 us; speedup vs baseline: 1.5224x; 1.5224x over previous
//
#include <hip/hip_runtime.h>

#define N_NODES 50000
#define N_EDGES 800000
#define D 128
#define HP 128              // histogram / fill partition blocks
#define EPB (N_EDGES / HP)  // 6250 edges per partition
#define NW (N_NODES / 2)    // 25000 packed u32 words (2 nodes/word)
#define NWB 98              // ceil(NW/256) reduce/scan blocks (512 nodes each)
#define NBLK 782            // ceil(N_NODES/64) fused gather+gemm blocks

typedef __attribute__((ext_vector_type(8))) short short8;   // 8 bf16
typedef __attribute__((ext_vector_type(4))) float f32x4;

__device__ __forceinline__ unsigned short f2bf(float f) {
    unsigned u = __float_as_uint(f);
    return (unsigned short)((u + 0x7FFFu + ((u >> 16) & 1u)) >> 16);  // RNE
}
__device__ __forceinline__ float bf2f(unsigned short h) {
    return __uint_as_float((unsigned)h << 16);
}

// accumulate 16 bf16 (packed in two uint4) into 16 f32
__device__ __forceinline__ void acc16(float* a, uint4 v0, uint4 v1) {
    unsigned w0 = v0.x, w1 = v0.y, w2 = v0.z, w3 = v0.w;
    unsigned w4 = v1.x, w5 = v1.y, w6 = v1.z, w7 = v1.w;
    a[0]  += __uint_as_float(w0 << 16);  a[1]  += __uint_as_float(w0 & 0xFFFF0000u);
    a[2]  += __uint_as_float(w1 << 16);  a[3]  += __uint_as_float(w1 & 0xFFFF0000u);
    a[4]  += __uint_as_float(w2 << 16);  a[5]  += __uint_as_float(w2 & 0xFFFF0000u);
    a[6]  += __uint_as_float(w3 << 16);  a[7]  += __uint_as_float(w3 & 0xFFFF0000u);
    a[8]  += __uint_as_float(w4 << 16);  a[9]  += __uint_as_float(w4 & 0xFFFF0000u);
    a[10] += __uint_as_float(w5 << 16);  a[11] += __uint_as_float(w5 & 0xFFFF0000u);
    a[12] += __uint_as_float(w6 << 16);  a[13] += __uint_as_float(w6 & 0xFFFF0000u);
    a[14] += __uint_as_float(w7 << 16);  a[15] += __uint_as_float(w7 & 0xFFFF0000u);
}

// ---- degrees via per-block LDS histograms (no global atomics) ----
// LDS word w packs: in[2w](b0) | out[2w](b1) | in[2w+1](b2) | out[2w+1](b3), u8 each.
__global__ __launch_bounds__(256) void k_hist(const int2* __restrict__ el2,
                                              unsigned int* __restrict__ partials) {
    __shared__ unsigned int h[NW];  // 100 KB
    int t = threadIdx.x;
    for (int i = t; i < NW / 4; i += 256) ((uint4*)h)[i] = make_uint4(0, 0, 0, 0);
    __syncthreads();
    const int2* p = el2 + blockIdx.x * EPB;
    for (int i = t; i < EPB; i += 256) {
        int2 st = p[i];
        atomicAdd(&h[st.x >> 1], 1u << ((st.x & 1) * 16));       // in-degree byte
        atomicAdd(&h[st.y >> 1], 256u << ((st.y & 1) * 16));     // out-degree byte
    }
    __syncthreads();
    uint4* dst = (uint4*)(partials + (size_t)blockIdx.x * NW);
    for (int i = t; i < NW / 4; i += 256) dst[i] = ((uint4*)h)[i];
}

// ---- fused: degree totals + cross-block exclusive prefixes (brel) + 512-node
// block sums + per-block degree histogram (dhistT[deg][blk], NO global atomics).
// NOTE: so = sum of (v>>8)&0x00FF00FF; out[2w] in so[15:0], out[2w+1] in so[31:16].
__global__ __launch_bounds__(256) void k_reduce(const unsigned int* __restrict__ partials,
                                                unsigned char* __restrict__ brel,
                                                int* __restrict__ deg_in,
                                                int* __restrict__ deg_out,
                                                int* __restrict__ blk_sum,
                                                int* __restrict__ dhistT) {
    __shared__ int sc[256];
    __shared__ int hb[256];
    int t = threadIdx.x;
    hb[t] = 0;
    int w = blockIdx.x * 256 + t;
    unsigned int si = 0, so = 0;
    if (w < NW) {
        for (int p = 0; p < HP; ++p) {
            unsigned pre = (so & 0xFFu) | (((so >> 16) & 0xFFu) << 8);
            ((unsigned short*)(brel + (size_t)p * N_NODES))[w] = (unsigned short)pre;
            unsigned int v = partials[p * NW + w];
            si += v & 0x00FF00FFu;
            so += (v >> 8) & 0x00FF00FFu;
        }
        *(int2*)&deg_in[2 * w]  = make_int2(si & 0xFFFF, si >> 16);
        *(int2*)&deg_out[2 * w] = make_int2(so & 0xFFFF, so >> 16);
    }
    __syncthreads();  // hb zeroed and visible
    if (w < NW) {
        int d0 = (int)(so & 0xFFFFu), d1 = (int)(so >> 16);
        atomicAdd(&hb[d0 < 255 ? d0 : 255], 1);   // LDS atomics only
        atomicAdd(&hb[d1 < 255 ? d1 : 255], 1);
    }
    sc[t] = (w < NW) ? (int)((so & 0xFFFFu) + (so >> 16)) : 0;
    __syncthreads();  // also orders the hb atomics above
    for (int s = 128; s > 0; s >>= 1) {
        if (t < s) sc[t] += sc[t + s];
        __syncthreads();
    }
    if (t == 0) blk_sum[blockIdx.x] = sc[0];
    // transposed histogram: contiguous per-degree rows for k_scan_b
    dhistT[t * NWB + blockIdx.x] = hb[t];
}

// exclusive scan of the NWB block sums + exclusive scan of the (deg DESC, blk)
// bins into absolute base offsets dcur[deg][blk] (single block)
__global__ void k_scan_b(const int* __restrict__ blk_sum, int* __restrict__ blk_off,
                         const int* __restrict__ dhistT, int* __restrict__ dcur) {
    __shared__ int sc[256];
    int t = threadIdx.x;
    int v = (t < NWB) ? blk_sum[t] : 0;
    sc[t] = v;
    __syncthreads();
    for (int off = 1; off < 256; off <<= 1) {
        int a = (t >= off) ? sc[t - off] : 0;
        __syncthreads();
        sc[t] += a;
        __syncthreads();
    }
    if (t < NWB) blk_off[t] = sc[t] - v;  // exclusive
    __syncthreads();
    // thread t owns degree d=t; rows of dhistT are contiguous (NWB ints)
    int s = 0;
    #pragma unroll
    for (int i = 0; i < NWB; ++i) s += dhistT[t * NWB + i];
    sc[255 - t] = s;  // descending-degree order: slot u = 255-d
    __syncthreads();
    for (int off = 1; off < 256; off <<= 1) {
        int a = (t >= off) ? sc[t - off] : 0;
        __syncthreads();
        sc[t] += a;
        __syncthreads();
    }
    int run = sc[255 - t] - s;  // exclusive prefix for degree t (descending layout)
    #pragma unroll
    for (int i = 0; i < NWB; ++i) {
        int c = dhistT[t * NWB + i];
        dcur[t * NWB + i] = run;
        run += c;
    }
}

// row_start over 512 nodes/block (2 per thread) + deterministic degree-sort
// placement: rank within (deg, blk) bin via LDS atomics, base from dcur.
// order[] is DESCENDING degree so heavy blocks launch first (better makespan).
// Any permutation is functionally correct — order only affects scheduling.
__global__ void k_scan_c(const int* __restrict__ deg_out, const int* __restrict__ blk_off,
                         int* __restrict__ row_start, const int* __restrict__ dcur,
                         int* __restrict__ order) {
    __shared__ int sc[256];
    __shared__ int lcnt[256];
    int t = threadIdx.x;
    lcnt[t] = 0;
    int w = blockIdx.x * 256 + t;
    int v0 = 0, v1 = 0;
    if (w < NW) { int2 d2 = *(const int2*)&deg_out[2 * w]; v0 = d2.x; v1 = d2.y; }
    int pair = v0 + v1;
    sc[t] = pair;
    __syncthreads();  // also makes lcnt zeroing visible
    for (int off = 1; off < 256; off <<= 1) {
        int a = (t >= off) ? sc[t - off] : 0;
        __syncthreads();
        sc[t] += a;
        __syncthreads();
    }
    if (w < NW) {
        int base = blk_off[blockIdx.x] + sc[t] - pair;
        *(int2*)&row_start[2 * w] = make_int2(base, base + v0);
        int d0 = v0 < 255 ? v0 : 255, d1 = v1 < 255 ? v1 : 255;
        int r0 = atomicAdd(&lcnt[d0], 1);  // LDS atomics only
        int r1 = atomicAdd(&lcnt[d1], 1);
        order[dcur[d0 * NWB + blockIdx.x] + r0] = 2 * w;
        order[dcur[d1 * NWB + blockIdx.x] + r1] = 2 * w + 1;
    }
}

// ---- counting-sort placement, NO global atomics; srcs stored as u16 ----
__global__ __launch_bounds__(256) void k_fill(const int2* __restrict__ el2,
                                              const int* __restrict__ row_start,
                                              const unsigned char* __restrict__ brel,
                                              unsigned short* __restrict__ srcs) {
    __shared__ unsigned int cur[NW];  // 100 KB packed u16 cursors
    int t = threadIdx.x;
    for (int i = t; i < NW / 4; i += 256) ((uint4*)cur)[i] = make_uint4(0, 0, 0, 0);
    __syncthreads();
    const int2* p = el2 + blockIdx.x * EPB;
    const unsigned char* br = brel + (size_t)blockIdx.x * N_NODES;
    for (int i = t; i < EPB; i += 256) {
        int2 st = p[i];
        int n = st.y;
        unsigned old = atomicAdd(&cur[n >> 1], 1u << ((n & 1) * 16));
        int rank = (old >> ((n & 1) * 16)) & 0xFFFF;
        srcs[row_start[n] + (int)br[n] + rank] = (unsigned short)st.x;
    }
}

// ---- xst[n][128] = bf16(rsqrt(deg_in[n]+1) * x[n][:]) — row-contiguous 256B rows ----
__global__ void k_prescale(const float4* __restrict__ x4, const int* __restrict__ deg_in,
                           uint4* __restrict__ xst) {
    int g = blockIdx.x * blockDim.x + threadIdx.x;  // N*16 groups of 8 elems
    int n = g >> 4, part = g & 15;
    float rs = rsqrtf((float)(deg_in[n] + 1));
    float4 a = x4[g * 2], c = x4[g * 2 + 1];
    uint4 o;
    o.x = f2bf(rs * a.x) | ((unsigned)f2bf(rs * a.y) << 16);
    o.y = f2bf(rs * a.z) | ((unsigned)f2bf(rs * a.w) << 16);
    o.z = f2bf(rs * c.x) | ((unsigned)f2bf(rs * c.y) << 16);
    o.w = f2bf(rs * c.z) | ((unsigned)f2bf(rs * c.w) << 16);
    xst[(size_t)n * 16 + part] = o;  // uint4 units (8 bf16)
}

// ---- fused gather + GEMM: per block 64 degree-sorted nodes.
// Phase 1: 8 lanes/node, each lane accumulates a 16-feature slice in f32 regs
//          (full 256B source row per edge, coalesced across the 8 lanes).
// Phase 2: scale by rd, cvt bf16 -> LDS A-tile, 8 waves do 64x128 MFMA GEMM,
//          bias+relu, scatter rows to out via order[].
__global__ __launch_bounds__(512, 4) void k_gg(const float* __restrict__ W,
                                               const float* __restrict__ bias,
                                               const unsigned short* __restrict__ xst,
                                               const unsigned short* __restrict__ srcs,
                                               const int* __restrict__ row_start,
                                               const int* __restrict__ deg_out,
                                               const int* __restrict__ order,
                                               float* __restrict__ out) {
    __shared__ unsigned short Wl[128 * 136];  // 34.8 KB
    __shared__ unsigned short As[64 * 136];   // 17.4 KB
    const int tid = threadIdx.x;

    // stage W -> bf16 (once per block)
    for (int i = tid; i < 128 * 32; i += 512) {
        int r = i >> 5, c = i & 31;
        float4 w4 = *(const float4*)&W[r * D + c * 4];
        ushort4 hh;
        hh.x = f2bf(w4.x); hh.y = f2bf(w4.y); hh.z = f2bf(w4.z); hh.w = f2bf(w4.w);
        *(ushort4*)&Wl[r * 136 + c * 4] = hh;
    }

    // ---- phase 1: gather ----
    const int slot = tid >> 3;            // As row 0..63
    const int d = tid & 7;                // 16-feature slice
    const int gslot = blockIdx.x * 64 + slot;
    float acc[16];
    #pragma unroll
    for (int i = 0; i < 16; ++i) acc[i] = 0.f;

    if (gslot < N_NODES) {
        const int node = order[gslot];
        const int cnt = deg_out[node];
        const uint4* xb = (const uint4*)xst;
        const int dof = d * 2;
        {   // self term (already rs-scaled)
            const uint4* xr = xb + (size_t)node * 16 + dof;
            acc16(acc, xr[0], xr[1]);
        }
        const unsigned short* p = srcs + row_start[node];
        int k = 0;
        for (; k + 4 <= cnt; k += 4) {
            int s0 = p[k], s1 = p[k + 1], s2 = p[k + 2], s3 = p[k + 3];
            const uint4* r0 = xb + (size_t)s0 * 16 + dof;
            const uint4* r1 = xb + (size_t)s1 * 16 + dof;
            const uint4* r2 = xb + (size_t)s2 * 16 + dof;
            const uint4* r3 = xb + (size_t)s3 * 16 + dof;
            uint4 a0 = r0[0], b0 = r0[1];
            uint4 a1 = r1[0], b1 = r1[1];
            uint4 a2 = r2[0], b2 = r2[1];
            uint4 a3 = r3[0], b3 = r3[1];
            acc16(acc, a0, b0); acc16(acc, a1, b1);
            acc16(acc, a2, b2); acc16(acc, a3, b3);
        }
        for (; k < cnt; ++k) {
            const uint4* r0 = xb + (size_t)p[k] * 16 + dof;
            acc16(acc, r0[0], r0[1]);
        }
        float rd = rsqrtf((float)(cnt + 1));
        #pragma unroll
        for (int i = 0; i < 16; ++i) acc[i] *= rd;
    }
    {   // pack 16 f32 -> 16 bf16 -> LDS (invalid slots write zeros; no early return!)
        unsigned wpk[8];
        #pragma unroll
        for (int i = 0; i < 8; ++i)
            wpk[i] = (unsigned)f2bf(acc[2 * i]) | ((unsigned)f2bf(acc[2 * i + 1]) << 16);
        uint4* dst = (uint4*)&As[slot * 136 + d * 16];
        dst[0] = make_uint4(wpk[0], wpk[1], wpk[2], wpk[3]);
        dst[1] = make_uint4(wpk[4], wpk[5], wpk[6], wpk[7]);
    }
    __syncthreads();

    // ---- phase 2: 64x128 GEMM, 8 waves = 4 row-tiles x 2 col-halves ----
    const int wv = tid >> 6, lane = tid & 63, ml = lane & 15, q = lane >> 4;
    const int rt = wv & 3, half = wv >> 2;
    const int arow = rt * 16 + ml;
    short8 a[4];
    #pragma unroll
    for (int kt = 0; kt < 4; ++kt)
        a[kt] = *(const short8*)&As[arow * 136 + kt * 32 + q * 8];

    f32x4 accm[4];
    #pragma unroll
    for (int jj = 0; jj < 4; ++jj) accm[jj] = (f32x4){0.f, 0.f, 0.f, 0.f};
    #pragma unroll
    for (int jj = 0; jj < 4; ++jj) {
        #pragma unroll
        for (int kt = 0; kt < 4; ++kt) {
            short8 bw = *(const short8*)&Wl[(half * 64 + jj * 16 + ml) * 136 + kt * 32 + q * 8];
            accm[jj] = __builtin_amdgcn_mfma_f32_16x16x32_bf16(a[kt], bw, accm[jj], 0, 0, 0);
        }
    }
    #pragma unroll
    for (int jj = 0; jj < 4; ++jj) {
        float bj = bias[half * 64 + jj * 16 + ml];
        #pragma unroll
        for (int r4 = 0; r4 < 4; ++r4) {
            int s = rt * 16 + q * 4 + r4;
            int gs = blockIdx.x * 64 + s;
            if (gs < N_NODES) {
                int nd = order[gs];
                float v = accm[jj][r4] + bj;
                out[nd * D + half * 64 + jj * 16 + ml] = v > 0.f ? v : 0.f;
            }
        }
    }
}

extern "C" void kernel_launch(void* const* d_in, const int* in_sizes, int n_in,
                              void* d_out, int out_size, void* d_ws, size_t ws_size,
                              hipStream_t stream) {
    const int*   el = (const int*)d_in[0];
    const float* x  = (const float*)d_in[1];
    const float* W  = (const float*)d_in[2];
    const float* b  = (const float*)d_in[3];
    float* out = (float*)d_out;

    // workspace layout (~34.6 MB)
    unsigned int* partials = (unsigned int*)d_ws;                            // HP*NW u32 = 12.8M
    unsigned short* xst    = (unsigned short*)(partials + (size_t)HP * NW);  // N*128 bf16 = 12.8M
    unsigned char* brel    = (unsigned char*)(xst + (size_t)N_NODES * D);    // HP*N u8 = 6.4M
    unsigned short* srcs   = (unsigned short*)(brel + (size_t)HP * N_NODES); // E u16 = 1.6M
    int* deg_in    = (int*)(srcs + N_EDGES);                                 // N
    int* deg_out   = deg_in + N_NODES;                                       // N
    int* row_start = deg_out + N_NODES;                                      // N
    int* blk_sum   = row_start + N_NODES;                                    // 256
    int* blk_off   = blk_sum + 256;                                          // 256
    int* dhistT    = blk_off + 256;                                          // 256*NWB = 25088
    int* dcur      = dhistT + 256 * NWB;                                     // 25088
    int* order     = dcur + 256 * NWB;                                       // N

    k_hist<<<HP, 256, 0, stream>>>((const int2*)el, partials);
    k_reduce<<<NWB, 256, 0, stream>>>(partials, brel, deg_in, deg_out, blk_sum, dhistT);
    k_scan_b<<<1, 256, 0, stream>>>(blk_sum, blk_off, dhistT, dcur);
    k_scan_c<<<NWB, 256, 0, stream>>>(deg_out, blk_off, row_start, dcur, order);
    k_prescale<<<N_NODES * 16 / 256, 256, 0, stream>>>((const float4*)x, deg_in, (uint4*)xst);
    k_fill<<<HP, 256, 0, stream>>>((const int2*)el, row_start, brel, srcs);
    k_gg<<<NBLK, 512, 0, stream>>>(W, b, xst, srcs, row_start, deg_out, order, out);
}